// Round 20
// baseline (2065.605 us; speedup 1.0000x reference)
//
#include <hip/hip_runtime.h>
#include <hip/hip_bf16.h>

#define B_ 16
#define T_ 12
#define N_ 2048
#define C_ 64
#define NW_ 10
#define K_ 6144  // WIN*N

#define NT32 192       // k32 phases
#define ALDS32 4096    // A elems per k32 LDS buffer (128 rows x 32 k)
#define BLDS32 10240   // B elems per k32 LDS buffer (320 cols x 32 k)

typedef __attribute__((ext_vector_type(8))) short bf16x8;
typedef __attribute__((ext_vector_type(4))) float f32x4;

__device__ __forceinline__ unsigned short f2bf(float f) {
  union { float f; unsigned int u; } v; v.f = f;
  unsigned int u = v.u;
  return (unsigned short)((u + 0x7FFFu + ((u >> 16) & 1u)) >> 16);  // RNE
}

__device__ __forceinline__ void gload16(const void* g, void* l) {
  __builtin_amdgcn_global_load_lds(
      (const __attribute__((address_space(1))) unsigned int*)g,
      (__attribute__((address_space(3))) unsigned int*)l, 16, 0, 0);
}

template<int N>
__device__ __forceinline__ void vmw() {
  if constexpr (N == 5) asm volatile("s_waitcnt vmcnt(5)" ::: "memory");
  else                  asm volatile("s_waitcnt vmcnt(0)" ::: "memory");
}

// ---- prep: x = data + temb + semb -> bf16 blocked layout, tile-through-LDS ----
__global__ __launch_bounds__(256) void prep_x3(const float* __restrict__ data,
                                               const float* __restrict__ temb,
                                               const float* __restrict__ semb,
                                               unsigned short* __restrict__ xbt2) {
  __shared__ unsigned short sx[64][72];   // [n][c], pitch 72
  int blk = blockIdx.x;          // 0..6143 = bt*32 + nb
  int nb = blk & 31;
  int bt = blk >> 5;
  int t = bt % T_;
  int n0 = nb * 64;
  int tid = threadIdx.x;
  const float* dbase = data + ((size_t)bt * N_ + n0) * C_;
  const float* sbase = semb + (size_t)n0 * C_;
  const float* tbase = temb + t * C_;
#pragma unroll
  for (int i = 0; i < 4; ++i) {
    int p = i * 256 + tid;
    int n = p >> 4, seg = p & 15;
    float4 dv = *(const float4*)(dbase + p * 4);
    float4 sv = *(const float4*)(sbase + p * 4);
    float4 tv = *(const float4*)(tbase + seg * 4);
    int c0 = seg * 4;
    sx[n][c0 + 0] = f2bf(dv.x + sv.x + tv.x);
    sx[n][c0 + 1] = f2bf(dv.y + sv.y + tv.y);
    sx[n][c0 + 2] = f2bf(dv.z + sv.z + tv.z);
    sx[n][c0 + 3] = f2bf(dv.w + sv.w + tv.w);
  }
  __syncthreads();
  unsigned short* obase = xbt2 + (size_t)blk * 4096;
#pragma unroll
  for (int i = 0; i < 2; ++i) {
    int q = i * 256 + tid;
    int o = q >> 6, c = q & 63;
    union { unsigned short s8[8]; uint4 v; } pk;
#pragma unroll
    for (int e = 0; e < 8; ++e) pk.s8[e] = sx[o * 8 + e][c];
    *(uint4*)(obase + (size_t)q * 8) = pk.v;
  }
}

// ---- prep: adj_mid -> bm128-tile granule layout, tile-through-LDS ----
__global__ __launch_bounds__(256) void prep_adj4(const float* __restrict__ adj,
                                                 unsigned short* __restrict__ adjb3) {
  __shared__ __align__(16) unsigned short sa[128][72];
  int blk = blockIdx.x;          // 0..1535 = bmt*96 + t
  int t = blk % 96;
  int bmt = blk / 96;
  int tid = threadIdx.x;
  const float* abase = adj + ((size_t)(N_ + bmt * 128)) * K_ + t * 64;
#pragma unroll
  for (int i = 0; i < 8; ++i) {
    int p = i * 256 + tid;
    int row = p >> 4, seg = p & 15;
    float4 v = *(const float4*)(abase + (size_t)row * K_ + seg * 4);
    int k0 = seg * 4;
    sa[row][k0 + 0] = f2bf(v.x);
    sa[row][k0 + 1] = f2bf(v.y);
    sa[row][k0 + 2] = f2bf(v.z);
    sa[row][k0 + 3] = f2bf(v.w);
  }
  __syncthreads();
  unsigned short* obase = adjb3 + (size_t)blk * 8192;
#pragma unroll
  for (int i = 0; i < 4; ++i) {
    int g = i * 256 + tid;
    int l15 = g & 15, l4 = (g >> 4) & 3;
    int c4 = g >> 6;
    int rg = c4 & 7, KK = (c4 >> 3) & 1;
    int row = rg * 16 + l15;
    int kcol = KK * 32 + l4 * 8;
    uint4 v = *(const uint4*)&sa[row][kcol];
    *(uint4*)(obase + (size_t)g * 8) = v;
  }
}

// ---- prep: W -> bf16 transposed [w][f][d][c] ----
__global__ __launch_bounds__(256) void prep_w(const float* __restrict__ W,
                                              unsigned short* __restrict__ wbt) {
  int idx = blockIdx.x * 256 + threadIdx.x;
  int c = idx & 63;
  int d = (idx >> 6) & 127;
  int wf = idx >> 13;
  float v = W[((size_t)wf * 64 + c) * 128 + d];
  wbt[idx] = f2bf(v);
}

// ---- fused GEMM + GLU: r13 K-loop (chunk-interleaved) + in-kernel epilogue ----
struct SegCtx {
  const unsigned short* Asrc;    // adjb3 + bmt*786432
  const unsigned short* Xroot;   // xbt2 + (b*T + w0)*C*N
  int lane, wid, l4, l15, fbase;
  int bconst[5];                 // B src offset per chunk (incl. lane term)
  int bch[5];                    // B LDS chunk elem offset: (c*4+wid)*512
};

template<int UA, int UB3>
__device__ __forceinline__ void phase32(const SegCtx& s, unsigned short* ldsA,
                                        unsigned short* ldsB, int u, f32x4 (&acc)[8][5]) {
  if (u + 1 < NT32) {            // stage A(u+1): 2 gloads
    const unsigned short* As = s.Asrc + (size_t)(u + 1) * 4096;
    unsigned short* Ad = ldsA + (UA ^ 1) * ALDS32;
#pragma unroll
    for (int ci = 0; ci < 2; ++ci) {
      int rg = s.wid * 2 + ci;
      gload16(As + rg * 512 + s.lane * 8, Ad + rg * 512);
    }
  }
  if (u + 2 < NT32) {            // stage B(u+2): 5 gloads
    const unsigned short* Bs = s.Xroot + (size_t)(u + 2) * 2048;
    unsigned short* Bd = ldsB + ((UB3 + 2) % 3) * BLDS32;
#pragma unroll
    for (int ci = 0; ci < 5; ++ci)
      gload16(Bs + s.bconst[ci], Bd + s.bch[ci]);
  }
  const unsigned short* Ab = ldsA + UA * ALDS32;
  const unsigned short* Bb = ldsB + UB3 * BLDS32;
  bf16x8 af[8], bfv[5];
#pragma unroll
  for (int c = 0; c < 5; ++c)
    bfv[c] = *(const bf16x8*)(Bb + s.bch[c] + s.fbase);
#pragma unroll
  for (int i = 0; i < 8; ++i)
    af[i] = *(const bf16x8*)(Ab + i * 512 + s.fbase);
  __builtin_amdgcn_s_setprio(1);
#pragma unroll
  for (int i = 0; i < 8; ++i)
#pragma unroll
    for (int c = 0; c < 5; ++c)
      acc[i][c] = __builtin_amdgcn_mfma_f32_16x16x32_bf16(af[i], bfv[c], acc[i][c], 0, 0, 0);
  __builtin_amdgcn_s_setprio(0);
  if (u < NT32 - 2) vmw<5>();
  else if (u == NT32 - 2) vmw<0>();
  if (u < NT32 - 1) {
    __builtin_amdgcn_s_barrier();
    __builtin_amdgcn_sched_barrier(0);
  }
}

__global__ __launch_bounds__(256, 2) void gemm_glu(const unsigned short* __restrict__ adjb3,
                                                   const unsigned short* __restrict__ xbt2,
                                                   const unsigned short* __restrict__ wbt,
                                                   const float* __restrict__ bias,
                                                   float* __restrict__ out) {
  __shared__ __align__(16) unsigned short lds[38912];   // 77,824B union
  unsigned short* ldsA = lds;                 // 2*ALDS32 = 8192 elems
  unsigned short* ldsB = lds + 2 * ALDS32;    // 3*BLDS32 = 30720 elems
  int bid = blockIdx.x;
  int bmt = bid & 15;               // bid&7 == bmt&7 -> XCD-resident A
  int bs = bid >> 4;
  int b = bs >> 1;
  int w0 = (bs & 1) * 5;
  int tid = threadIdx.x;
  int lane = tid & 63, wid = tid >> 6;
  SegCtx s;
  s.lane = lane; s.wid = wid;
  s.l4 = lane >> 4; s.l15 = lane & 15;
  s.fbase = s.l4 * 128 + s.l15 * 8;
  s.Asrc = adjb3 + (size_t)bmt * 786432;
  s.Xroot = xbt2 + ((size_t)(b * T_ + w0)) * C_ * N_;
  int bOffLane = s.l4 * 512 + s.l15 * 8;
#pragma unroll
  for (int ci = 0; ci < 5; ++ci) {
    // chunk cg = ci*4 + wid  (window ci, c-quarter wid)
    s.bconst[ci] = ci * 131072 + wid * 128 + bOffLane;
    s.bch[ci] = (ci * 4 + wid) * 512;
  }

  f32x4 acc[8][5];
#pragma unroll
  for (int i = 0; i < 8; ++i)
#pragma unroll
    for (int c = 0; c < 5; ++c) acc[i][c] = (f32x4)0.f;

  // prologue: A(0)->bufA0 (2), B(0)->bufB0 (5), B(1)->bufB1 (5); vmcnt(5): A0+B0 done
  __builtin_amdgcn_sched_barrier(0);
#pragma unroll
  for (int ci = 0; ci < 2; ++ci) {
    int rg = wid * 2 + ci;
    gload16(s.Asrc + rg * 512 + lane * 8, ldsA + rg * 512);
  }
#pragma unroll
  for (int ci = 0; ci < 5; ++ci)
    gload16(s.Xroot + s.bconst[ci], ldsB + s.bch[ci]);
#pragma unroll
  for (int ci = 0; ci < 5; ++ci)
    gload16(s.Xroot + 2048 + s.bconst[ci], ldsB + BLDS32 + s.bch[ci]);
  vmw<5>();
  __builtin_amdgcn_s_barrier();
  __builtin_amdgcn_sched_barrier(0);

  for (int it = 0; it < NT32 / 6; ++it) {
    int u = it * 6;
    phase32<0, 0>(s, ldsA, ldsB, u,     acc);
    phase32<1, 1>(s, ldsA, ldsB, u + 1, acc);
    phase32<0, 2>(s, ldsA, ldsB, u + 2, acc);
    phase32<1, 0>(s, ldsA, ldsB, u + 3, acc);
    phase32<0, 1>(s, ldsA, ldsB, u + 4, acc);
    phase32<1, 2>(s, ldsA, ldsB, u + 5, acc);
  }
  __builtin_amdgcn_s_barrier();   // all waves done with final phase's LDS reads

  // ---- fused epilogue: per window g: agg tile -> LDS; pre = agg@W + b; GLU; max; store
  unsigned short* agg = lds;                  // [128][72] bf16 = 18,432B
  float* scr = (float*)(lds + 9216);          // 4 waves x [32][68] f32 = 34,816B
  float* wscr = scr + wid * (32 * 68);
  float* outg0 = out + (((size_t)(b * NW_ + w0)) * N_ + bmt * 128) * C_;

  for (int g = 0; g < 5; ++g) {
    // dump acc[*][g] -> agg rows, cols wid*16+l15 (chunk-interleave => window g)
    int colw = wid * 16 + s.l15;
#pragma unroll
    for (int i = 0; i < 8; ++i)
#pragma unroll
      for (int q = 0; q < 4; ++q) {
        int row = i * 16 + s.l4 * 4 + q;
        agg[row * 72 + colw] = f2bf(acc[i][g][q]);
      }
    __builtin_amdgcn_s_barrier();
    // A-frags: wave owns rows wid*32..+32
    bf16x8 af2[2][2];
#pragma unroll
    for (int nf = 0; nf < 2; ++nf)
#pragma unroll
      for (int kk = 0; kk < 2; ++kk)
        af2[nf][kk] = *(const bf16x8*)&agg[(wid * 32 + nf * 16 + s.l15) * 72 + kk * 32 + s.l4 * 8];
    float omax2[2][4][4];
#pragma unroll
    for (int nf = 0; nf < 2; ++nf)
#pragma unroll
      for (int j = 0; j < 4; ++j)
#pragma unroll
        for (int q = 0; q < 4; ++q) omax2[nf][j][q] = -INFINITY;
    const unsigned short* Wg = wbt + (size_t)((w0 + g) * 3) * 8192;
    const float* biasg = bias + (size_t)((w0 + g) * 3) * 128;
    for (int f = 0; f < 3; ++f) {
      f32x4 a2[2][8];
#pragma unroll
      for (int nf = 0; nf < 2; ++nf)
#pragma unroll
        for (int j = 0; j < 8; ++j) a2[nf][j] = (f32x4)0.f;
      const unsigned short* Wf = Wg + f * 8192;
#pragma unroll
      for (int kk = 0; kk < 2; ++kk)
#pragma unroll
        for (int j = 0; j < 8; ++j) {
          bf16x8 bf2 = *(const bf16x8*)(Wf + (j * 16 + s.l15) * 64 + kk * 32 + s.l4 * 8);
#pragma unroll
          for (int nf = 0; nf < 2; ++nf)
            a2[nf][j] = __builtin_amdgcn_mfma_f32_16x16x32_bf16(af2[nf][kk], bf2, a2[nf][j], 0, 0, 0);
        }
#pragma unroll
      for (int j = 0; j < 4; ++j) {
        float bl = biasg[f * 128 + j * 16 + s.l15];
        float br = biasg[f * 128 + 64 + j * 16 + s.l15];
#pragma unroll
        for (int nf = 0; nf < 2; ++nf)
#pragma unroll
          for (int q = 0; q < 4; ++q) {
            float lhs = a2[nf][j][q] + bl;
            float rhs = a2[nf][j + 4][q] + br;
            float gv = lhs / (1.f + __expf(-rhs));
            omax2[nf][j][q] = fmaxf(omax2[nf][j][q], gv);
          }
      }
    }
    // wave-private LDS transpose -> coalesced float4 stores
#pragma unroll
    for (int nf = 0; nf < 2; ++nf)
#pragma unroll
      for (int j = 0; j < 4; ++j)
#pragma unroll
        for (int q = 0; q < 4; ++q)
          wscr[(nf * 16 + s.l4 * 4 + q) * 68 + j * 16 + s.l15] = omax2[nf][j][q];
    float* og = outg0 + (size_t)g * N_ * C_ + wid * 32 * C_;
#pragma unroll
    for (int it2 = 0; it2 < 8; ++it2) {
      int p = it2 * 64 + lane;
      int row = p >> 4, seg = p & 15;
      float4 v = *(const float4*)&wscr[row * 68 + seg * 4];
      *(float4*)(og + row * C_ + seg * 4) = v;
    }
    __builtin_amdgcn_s_barrier();   // WAR: before next window's agg dump
  }
}

extern "C" void kernel_launch(void* const* d_in, const int* in_sizes, int n_in,
                              void* d_out, int out_size, void* d_ws, size_t ws_size,
                              hipStream_t stream) {
  const float* data = (const float*)d_in[0];
  const float* adj  = (const float*)d_in[1];
  const float* temb = (const float*)d_in[2];
  const float* semb = (const float*)d_in[3];
  const float* W    = (const float*)d_in[4];
  const float* bias = (const float*)d_in[5];
  float* out = (float*)d_out;

  char* ws = (char*)d_ws;
  unsigned short* xbt2  = (unsigned short*)ws;               // 50,331,648 B
  unsigned short* adjb3 = (unsigned short*)(ws + 50331648);  // 25,165,824 B
  unsigned short* wbt   = (unsigned short*)(ws + 75497472);  //    491,520 B

  hipLaunchKernelGGL(prep_x3,   dim3(6144), dim3(256), 0, stream, data, temb, semb, xbt2);
  hipLaunchKernelGGL(prep_adj4, dim3(1536), dim3(256), 0, stream, adj, adjb3);
  hipLaunchKernelGGL(prep_w,    dim3(960),  dim3(256), 0, stream, W, wbt);
  hipLaunchKernelGGL(gemm_glu,  dim3(512),  dim3(256), 0, stream, adjb3, xbt2, wbt, bias, out);
}

// Round 21
// 306.867 us; speedup vs baseline: 6.7313x; 6.7313x over previous
//
#include <hip/hip_runtime.h>
#include <hip/hip_bf16.h>

#define B_ 16
#define T_ 12
#define N_ 2048
#define C_ 64
#define NW_ 10
#define K_ 6144  // WIN*N

#define NT32 192       // k32 phases
#define ALDS32 4096    // A elems per k32 LDS buffer (128 rows x 32 k)
#define BLDS32 10240   // B elems per k32 LDS buffer (320 cols x 32 k)

typedef __attribute__((ext_vector_type(8))) short bf16x8;
typedef __attribute__((ext_vector_type(4))) float f32x4;

__device__ __forceinline__ unsigned short f2bf(float f) {
  union { float f; unsigned int u; } v; v.f = f;
  unsigned int u = v.u;
  return (unsigned short)((u + 0x7FFFu + ((u >> 16) & 1u)) >> 16);  // RNE
}

__device__ __forceinline__ void gload16(const void* g, void* l) {
  __builtin_amdgcn_global_load_lds(
      (const __attribute__((address_space(1))) unsigned int*)g,
      (__attribute__((address_space(3))) unsigned int*)l, 16, 0, 0);
}

template<int N>
__device__ __forceinline__ void vmw() {
  if constexpr (N == 5) asm volatile("s_waitcnt vmcnt(5)" ::: "memory");
  else                  asm volatile("s_waitcnt vmcnt(0)" ::: "memory");
}

// ---- prep: x = data + temb + semb -> bf16 blocked layout, tile-through-LDS ----
__global__ __launch_bounds__(256) void prep_x3(const float* __restrict__ data,
                                               const float* __restrict__ temb,
                                               const float* __restrict__ semb,
                                               unsigned short* __restrict__ xbt2) {
  __shared__ unsigned short sx[64][72];   // [n][c], pitch 72
  int blk = blockIdx.x;          // 0..6143 = bt*32 + nb
  int nb = blk & 31;
  int bt = blk >> 5;
  int t = bt % T_;
  int n0 = nb * 64;
  int tid = threadIdx.x;
  const float* dbase = data + ((size_t)bt * N_ + n0) * C_;
  const float* sbase = semb + (size_t)n0 * C_;
  const float* tbase = temb + t * C_;
#pragma unroll
  for (int i = 0; i < 4; ++i) {
    int p = i * 256 + tid;
    int n = p >> 4, seg = p & 15;
    float4 dv = *(const float4*)(dbase + p * 4);
    float4 sv = *(const float4*)(sbase + p * 4);
    float4 tv = *(const float4*)(tbase + seg * 4);
    int c0 = seg * 4;
    sx[n][c0 + 0] = f2bf(dv.x + sv.x + tv.x);
    sx[n][c0 + 1] = f2bf(dv.y + sv.y + tv.y);
    sx[n][c0 + 2] = f2bf(dv.z + sv.z + tv.z);
    sx[n][c0 + 3] = f2bf(dv.w + sv.w + tv.w);
  }
  __syncthreads();
  unsigned short* obase = xbt2 + (size_t)blk * 4096;
#pragma unroll
  for (int i = 0; i < 2; ++i) {
    int q = i * 256 + tid;
    int o = q >> 6, c = q & 63;
    union { unsigned short s8[8]; uint4 v; } pk;
#pragma unroll
    for (int e = 0; e < 8; ++e) pk.s8[e] = sx[o * 8 + e][c];
    *(uint4*)(obase + (size_t)q * 8) = pk.v;
  }
}

// ---- prep: adj_mid -> bm128-tile granule layout, tile-through-LDS ----
__global__ __launch_bounds__(256) void prep_adj4(const float* __restrict__ adj,
                                                 unsigned short* __restrict__ adjb3) {
  __shared__ __align__(16) unsigned short sa[128][72];
  int blk = blockIdx.x;          // 0..1535 = bmt*96 + t
  int t = blk % 96;
  int bmt = blk / 96;
  int tid = threadIdx.x;
  const float* abase = adj + ((size_t)(N_ + bmt * 128)) * K_ + t * 64;
#pragma unroll
  for (int i = 0; i < 8; ++i) {
    int p = i * 256 + tid;
    int row = p >> 4, seg = p & 15;
    float4 v = *(const float4*)(abase + (size_t)row * K_ + seg * 4);
    int k0 = seg * 4;
    sa[row][k0 + 0] = f2bf(v.x);
    sa[row][k0 + 1] = f2bf(v.y);
    sa[row][k0 + 2] = f2bf(v.z);
    sa[row][k0 + 3] = f2bf(v.w);
  }
  __syncthreads();
  unsigned short* obase = adjb3 + (size_t)blk * 8192;
#pragma unroll
  for (int i = 0; i < 4; ++i) {
    int g = i * 256 + tid;
    int l15 = g & 15, l4 = (g >> 4) & 3;
    int c4 = g >> 6;
    int rg = c4 & 7, KK = (c4 >> 3) & 1;
    int row = rg * 16 + l15;
    int kcol = KK * 32 + l4 * 8;
    uint4 v = *(const uint4*)&sa[row][kcol];
    *(uint4*)(obase + (size_t)g * 8) = v;
  }
}

// ---- prep: W -> bf16 transposed [w][f][d][c] ----
__global__ __launch_bounds__(256) void prep_w(const float* __restrict__ W,
                                              unsigned short* __restrict__ wbt) {
  int idx = blockIdx.x * 256 + threadIdx.x;
  int c = idx & 63;
  int d = (idx >> 6) & 127;
  int wf = idx >> 13;
  float v = W[((size_t)wf * 64 + c) * 128 + d];
  wbt[idx] = f2bf(v);
}

// ---- main GEMM: r13 exact (best verified: 218.7us, MfmaUtil 54%) ----
struct SegCtx {
  const unsigned short* Asrc;    // adjb3 + bmt*786432
  const unsigned short* Xroot;   // xbt2 + (b*T + w0)*C*N
  int lane, wid, wid5, l4, l15, fbase;
  int bconst[5];                 // per-chunk B src offset (incl. lane term)
};

template<int UA, int UB3>
__device__ __forceinline__ void phase32(const SegCtx& s, unsigned short* ldsA,
                                        unsigned short* ldsB, int u, f32x4 (&acc)[8][5]) {
  if (u + 1 < NT32) {            // stage A(u+1): 2 gloads
    const unsigned short* As = s.Asrc + (size_t)(u + 1) * 4096;
    unsigned short* Ad = ldsA + (UA ^ 1) * ALDS32;
#pragma unroll
    for (int ci = 0; ci < 2; ++ci) {
      int rg = s.wid * 2 + ci;
      gload16(As + rg * 512 + s.lane * 8, Ad + rg * 512);
    }
  }
  if (u + 2 < NT32) {            // stage B(u+2): 5 gloads
    const unsigned short* Bs = s.Xroot + (size_t)(u + 2) * 2048;
    unsigned short* Bd = ldsB + ((UB3 + 2) % 3) * BLDS32;
#pragma unroll
    for (int ci = 0; ci < 5; ++ci) {
      int cg = s.wid5 + ci;
      gload16(Bs + s.bconst[ci], Bd + cg * 512);
    }
  }
  const unsigned short* Ab = ldsA + UA * ALDS32;
  const unsigned short* Bb = ldsB + UB3 * BLDS32;
  bf16x8 af[8], bfv[5];
#pragma unroll
  for (int c = 0; c < 5; ++c)
    bfv[c] = *(const bf16x8*)(Bb + (s.wid5 + c) * 512 + s.fbase);
#pragma unroll
  for (int i = 0; i < 8; ++i)
    af[i] = *(const bf16x8*)(Ab + i * 512 + s.fbase);
  __builtin_amdgcn_s_setprio(1);
#pragma unroll
  for (int i = 0; i < 8; ++i)
#pragma unroll
    for (int c = 0; c < 5; ++c)
      acc[i][c] = __builtin_amdgcn_mfma_f32_16x16x32_bf16(af[i], bfv[c], acc[i][c], 0, 0, 0);
  __builtin_amdgcn_s_setprio(0);
  if (u < NT32 - 2) vmw<5>();
  else if (u == NT32 - 2) vmw<0>();
  if (u < NT32 - 1) {
    __builtin_amdgcn_s_barrier();
    __builtin_amdgcn_sched_barrier(0);
  }
}

__global__ __launch_bounds__(256, 2) void gemm_agg(const unsigned short* __restrict__ adjb3,
                                                   const unsigned short* __restrict__ xbt2,
                                                   unsigned short* __restrict__ aggb) {
  __shared__ __align__(16) unsigned short ldsA[2 * ALDS32];   // 16KB
  __shared__ __align__(16) unsigned short ldsB[3 * BLDS32];   // 60KB
  int bid = blockIdx.x;
  int bmt = bid & 15;               // bid&7 == bmt&7 -> XCD-resident A (2x1.5MB)
  int bs = bid >> 4;
  int b = bs >> 1;
  int w0 = (bs & 1) * 5;
  int tid = threadIdx.x;
  SegCtx s;
  s.lane = tid & 63; s.wid = tid >> 6;
  s.wid5 = s.wid * 5;
  s.l4 = s.lane >> 4; s.l15 = s.lane & 15;
  s.fbase = s.l4 * 128 + s.l15 * 8;
  s.Asrc = adjb3 + (size_t)bmt * 786432;
  s.Xroot = xbt2 + ((size_t)(b * T_ + w0)) * C_ * N_;
  int bOffLane = s.l4 * 512 + s.l15 * 8;
#pragma unroll
  for (int ci = 0; ci < 5; ++ci) {
    int cg = s.wid5 + ci;
    s.bconst[ci] = (cg >> 2) * 131072 + (cg & 3) * 128 + bOffLane;
  }

  f32x4 acc[8][5];
#pragma unroll
  for (int i = 0; i < 8; ++i)
#pragma unroll
    for (int c = 0; c < 5; ++c) acc[i][c] = (f32x4)0.f;

  // prologue: A(0)->bufA0 (2), B(0)->bufB0 (5), B(1)->bufB1 (5); vmcnt(5): A0+B0 done
  __builtin_amdgcn_sched_barrier(0);
#pragma unroll
  for (int ci = 0; ci < 2; ++ci) {
    int rg = s.wid * 2 + ci;
    gload16(s.Asrc + rg * 512 + s.lane * 8, ldsA + rg * 512);
  }
#pragma unroll
  for (int ci = 0; ci < 5; ++ci)
    gload16(s.Xroot + s.bconst[ci], ldsB + (s.wid5 + ci) * 512);
#pragma unroll
  for (int ci = 0; ci < 5; ++ci)
    gload16(s.Xroot + 2048 + s.bconst[ci], ldsB + BLDS32 + (s.wid5 + ci) * 512);
  vmw<5>();
  __builtin_amdgcn_s_barrier();
  __builtin_amdgcn_sched_barrier(0);

  for (int it = 0; it < NT32 / 6; ++it) {
    int u = it * 6;
    phase32<0, 0>(s, ldsA, ldsB, u,     acc);
    phase32<1, 1>(s, ldsA, ldsB, u + 1, acc);
    phase32<0, 2>(s, ldsA, ldsB, u + 2, acc);
    phase32<1, 0>(s, ldsA, ldsB, u + 3, acc);
    phase32<0, 1>(s, ldsA, ldsB, u + 4, acc);
    phase32<1, 2>(s, ldsA, ldsB, u + 5, acc);
  }

  // C-write: bf16 agg [bw][n][c]
  unsigned short* Ob0 = aggb + (size_t)(b * NW_ + w0) * N_ * C_;
#pragma unroll
  for (int c = 0; c < 5; ++c) {
    int col = s.wid * 80 + c * 16 + s.l15;
    int g = col >> 6, cc = col & 63;
    unsigned short* Ob = Ob0 + (size_t)g * N_ * C_ + cc;
#pragma unroll
    for (int i = 0; i < 8; ++i) {
      int n0 = bmt * 128 + i * 16 + s.l4 * 4;
#pragma unroll
      for (int q = 0; q < 4; ++q)
        Ob[(size_t)(n0 + q) * C_] = f2bf(acc[i][c][q]);
    }
  }
}

// ---- epilogue: pre = agg @ W[w,f] + b; glu; max over f; LDS-transposed coalesced store ----
__global__ __launch_bounds__(256) void glu_out(const unsigned short* __restrict__ aggb,
                                               const unsigned short* __restrict__ wbt,
                                               const float* __restrict__ bias,
                                               float* __restrict__ out) {
  __shared__ __align__(16) unsigned short sW[3 * 128 * 64];  // 48KB; reused for store
  int bn = blockIdx.x, bw = blockIdx.y;
  int w = bw % NW_;
  int tid = threadIdx.x, lane = tid & 63, wid = tid >> 6;
  int lrow8 = lane >> 3, jl = lane & 7;
  int l15 = lane & 15, l4 = lane >> 4;
  const unsigned short* Wsrc = wbt + (size_t)w * 3 * 128 * 64;
  for (int ci = 0; ci < 12; ++ci) {
    int chunk = wid * 12 + ci;
    int row = chunk * 8 + lrow8;
    int jg = jl ^ (row & 7);
    gload16(Wsrc + (size_t)row * 64 + jg * 8, &sW[chunk * 512]);
  }
  const unsigned short* Abase = aggb + ((size_t)bw * N_ + bn * 128 + wid * 32) * C_;
  bf16x8 af[2][2];
  for (int i = 0; i < 2; ++i)
    for (int kh = 0; kh < 2; ++kh)
      af[i][kh] = *(const bf16x8*)(Abase + (size_t)(i * 16 + l15) * C_ + kh * 32 + l4 * 8);
  __syncthreads();

  float omax[2][4][4];
  for (int i = 0; i < 2; ++i)
    for (int j = 0; j < 4; ++j)
      for (int r = 0; r < 4; ++r) omax[i][j][r] = -INFINITY;

  for (int f = 0; f < 3; ++f) {
    f32x4 acc[2][8];
    for (int i = 0; i < 2; ++i)
      for (int j = 0; j < 8; ++j) acc[i][j] = (f32x4)0.f;
    for (int kh = 0; kh < 2; ++kh) {
      int gchunk = kh * 4 + l4;
      for (int j = 0; j < 8; ++j) {
        int row = f * 128 + j * 16 + l15;
        int ch = gchunk ^ (row & 7);
        bf16x8 bfr = *(const bf16x8*)&sW[row * 64 + ch * 8];
        for (int i = 0; i < 2; ++i)
          acc[i][j] = __builtin_amdgcn_mfma_f32_16x16x32_bf16(af[i][kh], bfr, acc[i][j], 0, 0, 0);
      }
    }
    for (int j = 0; j < 4; ++j) {
      float bl = bias[(w * 3 + f) * 128 + j * 16 + l15];
      float br = bias[(w * 3 + f) * 128 + 64 + j * 16 + l15];
      for (int i = 0; i < 2; ++i)
        for (int r = 0; r < 4; ++r) {
          float lhs = acc[i][j][r] + bl;
          float rhs = acc[i][j + 4][r] + br;
          float g = lhs / (1.f + __expf(-rhs));
          omax[i][j][r] = fmaxf(omax[i][j][r], g);
        }
    }
  }
  // store via LDS transpose: reuse sW as [wid][32 rows][pitch 68] f32
  __syncthreads();                      // all waves done reading sW
  float* tr = (float*)sW;
  float* wbase = tr + wid * 32 * 68;
#pragma unroll
  for (int i = 0; i < 2; ++i)
#pragma unroll
    for (int j = 0; j < 4; ++j)
#pragma unroll
      for (int r = 0; r < 4; ++r) {
        int row = i * 16 + l4 * 4 + r;
        int col = j * 16 + l15;
        wbase[row * 68 + col] = omax[i][j][r];
      }
  __syncthreads();
  float* Og = out + ((size_t)bw * N_ + bn * 128 + wid * 32) * C_;
#pragma unroll
  for (int it = 0; it < 8; ++it) {
    int p = it * 64 + lane;
    int row = p >> 4, seg = p & 15;
    float4 v = *(const float4*)&wbase[row * 68 + seg * 4];
    *(float4*)(Og + row * C_ + seg * 4) = v;
  }
}

extern "C" void kernel_launch(void* const* d_in, const int* in_sizes, int n_in,
                              void* d_out, int out_size, void* d_ws, size_t ws_size,
                              hipStream_t stream) {
  const float* data = (const float*)d_in[0];
  const float* adj  = (const float*)d_in[1];
  const float* temb = (const float*)d_in[2];
  const float* semb = (const float*)d_in[3];
  const float* W    = (const float*)d_in[4];
  const float* bias = (const float*)d_in[5];
  float* out = (float*)d_out;

  char* ws = (char*)d_ws;
  unsigned short* xbt2  = (unsigned short*)ws;               // 50,331,648 B
  unsigned short* adjb3 = (unsigned short*)(ws + 50331648);  // 25,165,824 B
  unsigned short* wbt   = (unsigned short*)(ws + 75497472);  //    491,520 B
  unsigned short* aggb  = (unsigned short*)(ws + 75988992);  // 41,943,040 B

  hipLaunchKernelGGL(prep_x3,   dim3(6144), dim3(256), 0, stream, data, temb, semb, xbt2);
  hipLaunchKernelGGL(prep_adj4, dim3(1536), dim3(256), 0, stream, adj, adjb3);
  hipLaunchKernelGGL(prep_w,    dim3(960),  dim3(256), 0, stream, W, wbt);
  hipLaunchKernelGGL(gemm_agg,  dim3(512),  dim3(256), 0, stream, adjb3, xbt2, aggb);
  hipLaunchKernelGGL(glu_out,   dim3(16, 160), dim3(256), 0, stream, aggb, wbt, bias, out);
}

// Round 22
// 303.359 us; speedup vs baseline: 6.8091x; 1.0116x over previous
//
#include <hip/hip_runtime.h>
#include <hip/hip_bf16.h>

#define B_ 16
#define T_ 12
#define N_ 2048
#define C_ 64
#define NW_ 10
#define K_ 6144  // WIN*N

#define NT32 192       // k32 phases
#define ALDS32 4096    // A elems per k32 LDS buffer (128 rows x 32 k)
#define BLDS32 10240   // B elems per k32 LDS buffer (320 cols x 32 k)

typedef __attribute__((ext_vector_type(8))) short bf16x8;
typedef __attribute__((ext_vector_type(4))) float f32x4;

__device__ __forceinline__ unsigned short f2bf(float f) {
  union { float f; unsigned int u; } v; v.f = f;
  unsigned int u = v.u;
  return (unsigned short)((u + 0x7FFFu + ((u >> 16) & 1u)) >> 16);  // RNE
}

__device__ __forceinline__ void gload16(const void* g, void* l) {
  __builtin_amdgcn_global_load_lds(
      (const __attribute__((address_space(1))) unsigned int*)g,
      (__attribute__((address_space(3))) unsigned int*)l, 16, 0, 0);
}

template<int N>
__device__ __forceinline__ void vmw() {
  if constexpr (N == 5) asm volatile("s_waitcnt vmcnt(5)" ::: "memory");
  else                  asm volatile("s_waitcnt vmcnt(0)" ::: "memory");
}

// ---- fused prep: x-blocked, adj-granule, W-transpose in ONE launch ----
// blk < 6144: x-prep (bt*32+nb tiles); 6144..7679: adj-prep; 7680..8639: W-prep.
__global__ __launch_bounds__(256) void prep_all(const float* __restrict__ data,
                                                const float* __restrict__ temb,
                                                const float* __restrict__ semb,
                                                const float* __restrict__ adj,
                                                const float* __restrict__ W,
                                                unsigned short* __restrict__ xbt2,
                                                unsigned short* __restrict__ adjb3,
                                                unsigned short* __restrict__ wbt) {
  __shared__ __align__(16) unsigned short sbuf[128 * 72];  // 18,432B union
  int blk = blockIdx.x;
  int tid = threadIdx.x;
  if (blk < 6144) {
    // ---- x-prep: tile (bt, nb) 64n x 64c ----
    unsigned short (*sx)[72] = (unsigned short (*)[72])sbuf;
    int nb = blk & 31;
    int bt = blk >> 5;
    int t = bt % T_;
    int n0 = nb * 64;
    const float* dbase = data + ((size_t)bt * N_ + n0) * C_;
    const float* sbase = semb + (size_t)n0 * C_;
    const float* tbase = temb + t * C_;
#pragma unroll
    for (int i = 0; i < 4; ++i) {
      int p = i * 256 + tid;
      int n = p >> 4, seg = p & 15;
      float4 dv = *(const float4*)(dbase + p * 4);
      float4 sv = *(const float4*)(sbase + p * 4);
      float4 tv = *(const float4*)(tbase + seg * 4);
      int c0 = seg * 4;
      sx[n][c0 + 0] = f2bf(dv.x + sv.x + tv.x);
      sx[n][c0 + 1] = f2bf(dv.y + sv.y + tv.y);
      sx[n][c0 + 2] = f2bf(dv.z + sv.z + tv.z);
      sx[n][c0 + 3] = f2bf(dv.w + sv.w + tv.w);
    }
    __syncthreads();
    unsigned short* obase = xbt2 + (size_t)blk * 4096;
#pragma unroll
    for (int i = 0; i < 2; ++i) {
      int q = i * 256 + tid;
      int o = q >> 6, c = q & 63;
      union { unsigned short s8[8]; uint4 v; } pk;
#pragma unroll
      for (int e = 0; e < 8; ++e) pk.s8[e] = sx[o * 8 + e][c];
      *(uint4*)(obase + (size_t)q * 8) = pk.v;
    }
  } else if (blk < 7680) {
    // ---- adj-prep: tile (bmt, t) 128m x 64k ----
    unsigned short (*sa)[72] = (unsigned short (*)[72])sbuf;
    int b2 = blk - 6144;
    int t = b2 % 96;
    int bmt = b2 / 96;
    const float* abase = adj + ((size_t)(N_ + bmt * 128)) * K_ + t * 64;
#pragma unroll
    for (int i = 0; i < 8; ++i) {
      int p = i * 256 + tid;
      int row = p >> 4, seg = p & 15;
      float4 v = *(const float4*)(abase + (size_t)row * K_ + seg * 4);
      int k0 = seg * 4;
      sa[row][k0 + 0] = f2bf(v.x);
      sa[row][k0 + 1] = f2bf(v.y);
      sa[row][k0 + 2] = f2bf(v.z);
      sa[row][k0 + 3] = f2bf(v.w);
    }
    __syncthreads();
    unsigned short* obase = adjb3 + (size_t)b2 * 8192;
#pragma unroll
    for (int i = 0; i < 4; ++i) {
      int g = i * 256 + tid;
      int l15 = g & 15, l4 = (g >> 4) & 3;
      int c4 = g >> 6;
      int rg = c4 & 7, KK = (c4 >> 3) & 1;
      int row = rg * 16 + l15;
      int kcol = KK * 32 + l4 * 8;
      uint4 v = *(const uint4*)&sa[row][kcol];
      *(uint4*)(obase + (size_t)g * 8) = v;
    }
  } else {
    // ---- W-prep ----
    int idx = (blk - 7680) * 256 + tid;
    int c = idx & 63;
    int d = (idx >> 6) & 127;
    int wf = idx >> 13;
    float v = W[((size_t)wf * 64 + c) * 128 + d];
    wbt[idx] = f2bf(v);
  }
}

// ---- main GEMM: r13 exact (best verified: 218.7us, MfmaUtil 54%) ----
struct SegCtx {
  const unsigned short* Asrc;    // adjb3 + bmt*786432
  const unsigned short* Xroot;   // xbt2 + (b*T + w0)*C*N
  int lane, wid, wid5, l4, l15, fbase;
  int bconst[5];                 // per-chunk B src offset (incl. lane term)
};

template<int UA, int UB3>
__device__ __forceinline__ void phase32(const SegCtx& s, unsigned short* ldsA,
                                        unsigned short* ldsB, int u, f32x4 (&acc)[8][5]) {
  if (u + 1 < NT32) {            // stage A(u+1): 2 gloads
    const unsigned short* As = s.Asrc + (size_t)(u + 1) * 4096;
    unsigned short* Ad = ldsA + (UA ^ 1) * ALDS32;
#pragma unroll
    for (int ci = 0; ci < 2; ++ci) {
      int rg = s.wid * 2 + ci;
      gload16(As + rg * 512 + s.lane * 8, Ad + rg * 512);
    }
  }
  if (u + 2 < NT32) {            // stage B(u+2): 5 gloads
    const unsigned short* Bs = s.Xroot + (size_t)(u + 2) * 2048;
    unsigned short* Bd = ldsB + ((UB3 + 2) % 3) * BLDS32;
#pragma unroll
    for (int ci = 0; ci < 5; ++ci) {
      int cg = s.wid5 + ci;
      gload16(Bs + s.bconst[ci], Bd + cg * 512);
    }
  }
  const unsigned short* Ab = ldsA + UA * ALDS32;
  const unsigned short* Bb = ldsB + UB3 * BLDS32;
  bf16x8 af[8], bfv[5];
#pragma unroll
  for (int c = 0; c < 5; ++c)
    bfv[c] = *(const bf16x8*)(Bb + (s.wid5 + c) * 512 + s.fbase);
#pragma unroll
  for (int i = 0; i < 8; ++i)
    af[i] = *(const bf16x8*)(Ab + i * 512 + s.fbase);
  __builtin_amdgcn_s_setprio(1);
#pragma unroll
  for (int i = 0; i < 8; ++i)
#pragma unroll
    for (int c = 0; c < 5; ++c)
      acc[i][c] = __builtin_amdgcn_mfma_f32_16x16x32_bf16(af[i], bfv[c], acc[i][c], 0, 0, 0);
  __builtin_amdgcn_s_setprio(0);
  if (u < NT32 - 2) vmw<5>();
  else if (u == NT32 - 2) vmw<0>();
  if (u < NT32 - 1) {
    __builtin_amdgcn_s_barrier();
    __builtin_amdgcn_sched_barrier(0);
  }
}

__global__ __launch_bounds__(256, 2) void gemm_agg(const unsigned short* __restrict__ adjb3,
                                                   const unsigned short* __restrict__ xbt2,
                                                   unsigned short* __restrict__ aggb) {
  __shared__ __align__(16) unsigned short ldsA[2 * ALDS32];   // 16KB
  __shared__ __align__(16) unsigned short ldsB[3 * BLDS32];   // 60KB
  int bid = blockIdx.x;
  int bmt = bid & 15;               // bid&7 == bmt&7 -> XCD-resident A (2x1.5MB)
  int bs = bid >> 4;
  int b = bs >> 1;
  int w0 = (bs & 1) * 5;
  int tid = threadIdx.x;
  SegCtx s;
  s.lane = tid & 63; s.wid = tid >> 6;
  s.wid5 = s.wid * 5;
  s.l4 = s.lane >> 4; s.l15 = s.lane & 15;
  s.fbase = s.l4 * 128 + s.l15 * 8;
  s.Asrc = adjb3 + (size_t)bmt * 786432;
  s.Xroot = xbt2 + ((size_t)(b * T_ + w0)) * C_ * N_;
  int bOffLane = s.l4 * 512 + s.l15 * 8;
#pragma unroll
  for (int ci = 0; ci < 5; ++ci) {
    int cg = s.wid5 + ci;
    s.bconst[ci] = (cg >> 2) * 131072 + (cg & 3) * 128 + bOffLane;
  }

  f32x4 acc[8][5];
#pragma unroll
  for (int i = 0; i < 8; ++i)
#pragma unroll
    for (int c = 0; c < 5; ++c) acc[i][c] = (f32x4)0.f;

  // prologue: A(0)->bufA0 (2), B(0)->bufB0 (5), B(1)->bufB1 (5); vmcnt(5): A0+B0 done
  __builtin_amdgcn_sched_barrier(0);
#pragma unroll
  for (int ci = 0; ci < 2; ++ci) {
    int rg = s.wid * 2 + ci;
    gload16(s.Asrc + rg * 512 + s.lane * 8, ldsA + rg * 512);
  }
#pragma unroll
  for (int ci = 0; ci < 5; ++ci)
    gload16(s.Xroot + s.bconst[ci], ldsB + (s.wid5 + ci) * 512);
#pragma unroll
  for (int ci = 0; ci < 5; ++ci)
    gload16(s.Xroot + 2048 + s.bconst[ci], ldsB + BLDS32 + (s.wid5 + ci) * 512);
  vmw<5>();
  __builtin_amdgcn_s_barrier();
  __builtin_amdgcn_sched_barrier(0);

  for (int it = 0; it < NT32 / 6; ++it) {
    int u = it * 6;
    phase32<0, 0>(s, ldsA, ldsB, u,     acc);
    phase32<1, 1>(s, ldsA, ldsB, u + 1, acc);
    phase32<0, 2>(s, ldsA, ldsB, u + 2, acc);
    phase32<1, 0>(s, ldsA, ldsB, u + 3, acc);
    phase32<0, 1>(s, ldsA, ldsB, u + 4, acc);
    phase32<1, 2>(s, ldsA, ldsB, u + 5, acc);
  }

  // C-write: bf16 agg [bw][n][c]
  unsigned short* Ob0 = aggb + (size_t)(b * NW_ + w0) * N_ * C_;
#pragma unroll
  for (int c = 0; c < 5; ++c) {
    int col = s.wid * 80 + c * 16 + s.l15;
    int g = col >> 6, cc = col & 63;
    unsigned short* Ob = Ob0 + (size_t)g * N_ * C_ + cc;
#pragma unroll
    for (int i = 0; i < 8; ++i) {
      int n0 = bmt * 128 + i * 16 + s.l4 * 4;
#pragma unroll
      for (int q = 0; q < 4; ++q)
        Ob[(size_t)(n0 + q) * C_] = f2bf(acc[i][c][q]);
    }
  }
}

// ---- epilogue: pre = agg @ W[w,f] + b; glu; max over f; LDS-transposed coalesced store ----
__global__ __launch_bounds__(256) void glu_out(const unsigned short* __restrict__ aggb,
                                               const unsigned short* __restrict__ wbt,
                                               const float* __restrict__ bias,
                                               float* __restrict__ out) {
  __shared__ __align__(16) unsigned short sW[3 * 128 * 64];  // 48KB; reused for store
  int bn = blockIdx.x, bw = blockIdx.y;
  int w = bw % NW_;
  int tid = threadIdx.x, lane = tid & 63, wid = tid >> 6;
  int lrow8 = lane >> 3, jl = lane & 7;
  int l15 = lane & 15, l4 = lane >> 4;
  const unsigned short* Wsrc = wbt + (size_t)w * 3 * 128 * 64;
  for (int ci = 0; ci < 12; ++ci) {
    int chunk = wid * 12 + ci;
    int row = chunk * 8 + lrow8;
    int jg = jl ^ (row & 7);
    gload16(Wsrc + (size_t)row * 64 + jg * 8, &sW[chunk * 512]);
  }
  const unsigned short* Abase = aggb + ((size_t)bw * N_ + bn * 128 + wid * 32) * C_;
  bf16x8 af[2][2];
  for (int i = 0; i < 2; ++i)
    for (int kh = 0; kh < 2; ++kh)
      af[i][kh] = *(const bf16x8*)(Abase + (size_t)(i * 16 + l15) * C_ + kh * 32 + l4 * 8);
  __syncthreads();

  float omax[2][4][4];
  for (int i = 0; i < 2; ++i)
    for (int j = 0; j < 4; ++j)
      for (int r = 0; r < 4; ++r) omax[i][j][r] = -INFINITY;

  for (int f = 0; f < 3; ++f) {
    f32x4 acc[2][8];
    for (int i = 0; i < 2; ++i)
      for (int j = 0; j < 8; ++j) acc[i][j] = (f32x4)0.f;
    for (int kh = 0; kh < 2; ++kh) {
      int gchunk = kh * 4 + l4;
      for (int j = 0; j < 8; ++j) {
        int row = f * 128 + j * 16 + l15;
        int ch = gchunk ^ (row & 7);
        bf16x8 bfr = *(const bf16x8*)&sW[row * 64 + ch * 8];
        for (int i = 0; i < 2; ++i)
          acc[i][j] = __builtin_amdgcn_mfma_f32_16x16x32_bf16(af[i][kh], bfr, acc[i][j], 0, 0, 0);
      }
    }
    for (int j = 0; j < 4; ++j) {
      float bl = bias[(w * 3 + f) * 128 + j * 16 + l15];
      float br = bias[(w * 3 + f) * 128 + 64 + j * 16 + l15];
      for (int i = 0; i < 2; ++i)
        for (int r = 0; r < 4; ++r) {
          float lhs = acc[i][j][r] + bl;
          float rhs = acc[i][j + 4][r] + br;
          float g = lhs / (1.f + __expf(-rhs));
          omax[i][j][r] = fmaxf(omax[i][j][r], g);
        }
    }
  }
  // store via LDS transpose: reuse sW as [wid][32 rows][pitch 68] f32
  __syncthreads();                      // all waves done reading sW
  float* tr = (float*)sW;
  float* wbase = tr + wid * 32 * 68;
#pragma unroll
  for (int i = 0; i < 2; ++i)
#pragma unroll
    for (int j = 0; j < 4; ++j)
#pragma unroll
      for (int r = 0; r < 4; ++r) {
        int row = i * 16 + l4 * 4 + r;
        int col = j * 16 + l15;
        wbase[row * 68 + col] = omax[i][j][r];
      }
  __syncthreads();
  float* Og = out + ((size_t)bw * N_ + bn * 128 + wid * 32) * C_;
#pragma unroll
  for (int it = 0; it < 8; ++it) {
    int p = it * 64 + lane;
    int row = p >> 4, seg = p & 15;
    float4 v = *(const float4*)&wbase[row * 68 + seg * 4];
    *(float4*)(Og + row * C_ + seg * 4) = v;
  }
}

extern "C" void kernel_launch(void* const* d_in, const int* in_sizes, int n_in,
                              void* d_out, int out_size, void* d_ws, size_t ws_size,
                              hipStream_t stream) {
  const float* data = (const float*)d_in[0];
  const float* adj  = (const float*)d_in[1];
  const float* temb = (const float*)d_in[2];
  const float* semb = (const float*)d_in[3];
  const float* W    = (const float*)d_in[4];
  const float* bias = (const float*)d_in[5];
  float* out = (float*)d_out;

  char* ws = (char*)d_ws;
  unsigned short* xbt2  = (unsigned short*)ws;               // 50,331,648 B
  unsigned short* adjb3 = (unsigned short*)(ws + 50331648);  // 25,165,824 B
  unsigned short* wbt   = (unsigned short*)(ws + 75497472);  //    491,520 B
  unsigned short* aggb  = (unsigned short*)(ws + 75988992);  // 41,943,040 B

  hipLaunchKernelGGL(prep_all, dim3(8640), dim3(256), 0, stream,
                     data, temb, semb, adj, W, xbt2, adjb3, wbt);
  hipLaunchKernelGGL(gemm_agg, dim3(512),  dim3(256), 0, stream, adjb3, xbt2, aggb);
  hipLaunchKernelGGL(glu_out,  dim3(16, 160), dim3(256), 0, stream, aggb, wbt, bias, out);
}